// Round 3
// baseline (655.839 us; speedup 1.0000x reference)
//
#include <hip/hip_runtime.h>

static constexpr int MM  = 90000;  // cells
static constexpr int TT  = 150;    // steps
static constexpr int BS  = 256;    // threads per block (4 waves)
static constexpr int CPT = 4;      // cells per thread
static constexpr int CPB = BS * CPT;               // 1024 cells per block
static constexpr int NB  = (MM + CPB - 1) / CPB;   // 88 blocks
static constexpr int WPB = BS / 64;                // 4 waves per block
static constexpr int NWAVE = NB * WPB;             // 352 waves
static constexpr int WPAGES = 384;                 // 64 lanes x 6 loads (352 real + 32 sentinel)
static constexpr int PAGE_U32 = 2048;              // 8 KB page -> own channel
static constexpr int DUMMY_OFF = 1024;             // words [1024..2047] preset to 1 in EVERY page

typedef unsigned int u32x4 __attribute__((ext_vector_type(4)));

// Persistent device globals, re-initialized by init_ws_kernel EVERY launch.
// g_wmax[gw][t]: wave gw's |u|+c max at step t (nonzero by construction, c>=4e-4).
// One writer per 8KB page -> no line sharing. Words >=1024 preset 1 (per-lane
// dummy poll targets); pages >=NWAVE fully preset 1 (sentinels).
__device__ __attribute__((aligned(128))) unsigned int g_wmax[WPAGES][PAGE_U32];
// g_edge[b][t*8 + {0..3:L, 4..7:R}] = {A,Q,F,0} as one 16B unit, single
// global_store_dwordx4 -> no tearing window. Flag = (A!=0 && F!=0).
__device__ __attribute__((aligned(128))) unsigned int g_edge[NB][PAGE_U32];

__device__ __forceinline__ float softplus_f(float x) {
    return fmaxf(x, 0.0f) + log1pf(expf(-fabsf(x)));
}
#define AG_STORE32(p, v) __hip_atomic_store((p), (v), __ATOMIC_RELAXED, __HIP_MEMORY_SCOPE_AGENT)

// 6 wmax dword loads + 1 halo dwordx4, issued together. ISSUE7 = non-blocking
// (latency hidden under the overlap compute); POLL7 = same + fused vmcnt(0).
#define ISSUE7(x0,x1,x2,x3,x4,x5,h,p0,p1,p2,p3,p4,p5,ph)                        \
    asm volatile("global_load_dword %0, %7, off sc1\n\t"                        \
                 "global_load_dword %1, %8, off sc1\n\t"                        \
                 "global_load_dword %2, %9, off sc1\n\t"                        \
                 "global_load_dword %3, %10, off sc1\n\t"                       \
                 "global_load_dword %4, %11, off sc1\n\t"                       \
                 "global_load_dword %5, %12, off sc1\n\t"                       \
                 "global_load_dwordx4 %6, %13, off sc1"                         \
                 : "=&v"(x0),"=&v"(x1),"=&v"(x2),"=&v"(x3),"=&v"(x4),"=&v"(x5),"=&v"(h) \
                 : "v"(p0),"v"(p1),"v"(p2),"v"(p3),"v"(p4),"v"(p5),"v"(ph)      \
                 : "memory")
#define POLL7(x0,x1,x2,x3,x4,x5,h,p0,p1,p2,p3,p4,p5,ph)                         \
    asm volatile("global_load_dword %0, %7, off sc1\n\t"                        \
                 "global_load_dword %1, %8, off sc1\n\t"                        \
                 "global_load_dword %2, %9, off sc1\n\t"                        \
                 "global_load_dword %3, %10, off sc1\n\t"                       \
                 "global_load_dword %4, %11, off sc1\n\t"                       \
                 "global_load_dword %5, %12, off sc1\n\t"                       \
                 "global_load_dwordx4 %6, %13, off sc1\n\t"                     \
                 "s_waitcnt vmcnt(0)"                                           \
                 : "=&v"(x0),"=&v"(x1),"=&v"(x2),"=&v"(x3),"=&v"(x4),"=&v"(x5),"=&v"(h) \
                 : "v"(p0),"v"(p1),"v"(p2),"v"(p3),"v"(p4),"v"(p5),"v"(ph)      \
                 : "memory")
#define ISSUE1(h, ph)                                                           \
    asm volatile("global_load_dwordx4 %0, %1, off sc1"                          \
                 : "=&v"(h) : "v"(ph) : "memory")
#define POLL1(h, ph)                                                            \
    asm volatile("global_load_dwordx4 %0, %1, off sc1\n\t"                      \
                 "s_waitcnt vmcnt(0)"                                           \
                 : "=&v"(h) : "v"(ph) : "memory")
#define WAITVM()  do { asm volatile("s_waitcnt vmcnt(0)" ::: "memory");         \
                       __builtin_amdgcn_sched_barrier(0); } while (0)
#define FENCE_LDS() asm volatile("s_waitcnt lgkmcnt(0)" ::: "memory")
#define STORE_X4(p, v)                                                          \
    asm volatile("global_store_dwordx4 %0, %1, off sc1" :: "v"(p), "v"(v) : "memory")

// 64-lane max reduce in 6 DPP stages; lane 63 ends with the full max. Values >= 0.
#define DPP_MAX(x, ctrl, rm, bm)                                                \
    x = fmaxf(x, __int_as_float(__builtin_amdgcn_update_dpp(                    \
                     0, __float_as_int(x), (ctrl), (rm), (bm), true)))
__device__ __forceinline__ float wave_max64(float x) {
    DPP_MAX(x, 0x111, 0xf, 0xf);   // row_shr:1
    DPP_MAX(x, 0x112, 0xf, 0xf);   // row_shr:2
    DPP_MAX(x, 0x114, 0xf, 0xe);   // row_shr:4
    DPP_MAX(x, 0x118, 0xf, 0xc);   // row_shr:8
    DPP_MAX(x, 0x142, 0xa, 0xf);   // row_bcast:15
    DPP_MAX(x, 0x143, 0xc, 0xf);   // row_bcast:31 -> lane 63 = full max
    return x;
}

__global__ void init_ws_kernel() {
    int i = blockIdx.x * blockDim.x + threadIdx.x;
    int stride = gridDim.x * blockDim.x;
    unsigned int* pw = &g_wmax[0][0];
    for (int j = i; j < WPAGES * PAGE_U32; j += stride)
        pw[j] = (((j >> 11) < NWAVE) && ((j & (PAGE_U32 - 1)) < DUMMY_OFF)) ? 0u : 1u;
    unsigned int* pe = &g_edge[0][0];
    for (int j = i; j < NB * PAGE_U32; j += stride) pe[j] = 0u;
}

__global__ void __launch_bounds__(BS) sim_kernel(
    const float* __restrict__ Rs,
    const float* __restrict__ sim_dat,
    const float* __restrict__ sdc,
    const float* __restrict__ inflow,
    float* __restrict__ out)
{
    __shared__ float sE[2][WPB][2][3];         // [parity][wave][L/R edge cell][A,Q,F]
    __shared__ unsigned long long s_lamw[TT];  // per-step {lam,w} value-flag (wave0 -> others)
    __shared__ float s_inflow[TT];

    const int b    = blockIdx.x;
    const int tid  = threadIdx.x;
    const int wv   = tid >> 6;
    const int lane = tid & 63;
    const int base = b * CPB + tid * CPT;   // 4 contiguous cells per thread
    const int gw   = b * WPB + wv;          // global wave id -> own wmax page

    for (int j = tid; j < TT; j += BS) { s_inflow[j] = inflow[j]; s_lamw[j] = 0ull; }

    // ---- per-cell constants & initial state (registers all sim) ----
    float A[CPT], Q[CPT], A0v[CPT], bet[CPT], cbv[CPT], k2v[CPT], sq[CPT], FQ[CPT];
    bool  act[CPT];
    #pragma unroll
    for (int c = 0; c < CPT; ++c) {
        int i = base + c;
        act[c] = (i < MM);
        if (act[c]) {
            A[c]   = fmaxf(sim_dat[i], 1e-6f);
            Q[c]   = 0.1f * sim_dat[MM + i];
            A0v[c] = sdc[i] + 0.5f;
            bet[c] = sdc[MM + i] + 1.0f;
        } else { A[c] = 1.0f; Q[c] = 0.0f; A0v[c] = 1.0f; bet[c] = 1.0f; }
        cbv[c] = (0.5f * bet[c]) / 1060.0f;     // (0.5*beta)/RHO  (ref op order)
        k2v[c] = bet[c] / (3180.0f * A0v[c]);   // beta/(3*RHO*A0)
    }
    const bool isStart = (base == 0) | (base == 30000) | (base == 60000);                  // cell 0
    const bool isEnd   = (base + 3 == 29999) | (base + 3 == 59999) | (base + 3 == 89999);  // cell 3
    const int midSlot = (base == 15000) ? 0 : (base == 45000) ? 1 : (base == 75000) ? 2 : -1;
    float Rtot = 1.0f;
    if (isEnd) {
        int i3 = base + 3;
        float R1 = sdc[7 * MM + i3] + 0.5f;
        float R2 = sdc[8 * MM + i3] + 0.5f;
        if (i3 == 59999)      { R1 *= softplus_f(Rs[0]); R2 *= softplus_f(Rs[1]); }
        else if (i3 == 89999) { R1 *= softplus_f(Rs[2]); R2 *= softplus_f(Rs[3]); }
        Rtot = R1 + R2;
    }

    const bool pubL = (tid == 0) && (b > 0);            // publish my left edge (read by b-1)
    const bool pubR = (tid == BS - 1) && (b < NB - 1);  // publish my right edge (read by b+1)

    // ---- initial derived state + t=0 publishes ----
    float s4 = 0.0f;
    #pragma unroll
    for (int c = 0; c < CPT; ++c) {
        sq[c] = sqrtf(A[c] / A0v[c]);
        float uu = Q[c] / A[c];
        float cc = sqrtf(cbv[c] * sq[c]);
        FQ[c] = Q[c] * uu + k2v[c] * A[c] * sq[c];
        s4 = fmaxf(s4, act[c] ? (fabsf(uu) + cc) : 0.0f);
    }
    if (pubL) { u32x4 ev = { __float_as_uint(A[0]), __float_as_uint(Q[0]), __float_as_uint(FQ[0]), 0u };
                STORE_X4(&g_edge[b][0], ev); }
    if (pubR) { u32x4 ev = { __float_as_uint(A[3]), __float_as_uint(Q[3]), __float_as_uint(FQ[3]), 0u };
                STORE_X4(&g_edge[b][4], ev); }
    if (lane == 0)       { sE[0][wv][0][0] = A[0]; sE[0][wv][0][1] = Q[0]; sE[0][wv][0][2] = FQ[0]; }
    else if (lane == 63) { sE[0][wv][1][0] = A[3]; sE[0][wv][1][1] = Q[3]; sE[0][wv][1][2] = FQ[3]; }
    {
        float red = wave_max64(s4);
        FENCE_LDS();   // sE writes complete BEFORE wmax publish (ordering protocol)
        if (lane == 63) AG_STORE32(&g_wmax[gw][0], __float_as_uint(red));
    }
    __syncthreads();   // the ONLY barrier: orders s_lamw zero-init + s_inflow fill

    for (int t = 0; t < TT; ++t) {
        const int par = t & 1, npar = par ^ 1;

        // ===== issue first poll sample (NON-blocking) =====
        unsigned int x0, x1, x2, x3, x4, x5;
        u32x4 h;
        const unsigned int *p0, *p1, *p2, *p3, *p4, *p5, *ph;
        if (wv == 0) {
            p0 = &g_wmax[lane      ][t];  p1 = &g_wmax[lane +  64][t];
            p2 = &g_wmax[lane + 128][t];  p3 = &g_wmax[lane + 192][t];
            p4 = &g_wmax[lane + 256][t];  p5 = &g_wmax[lane + 320][t];
            ph = (lane == 0 && b > 0) ? &g_edge[b - 1][t * 8 + 4]   // left nbr R-edge
                                      : &g_wmax[lane][DUMMY_OFF];   // per-lane dummy (preset 1s)
            ISSUE7(x0, x1, x2, x3, x4, x5, h, p0, p1, p2, p3, p4, p5, ph);
        } else if (wv == WPB - 1) {
            ph = (lane == 63 && b < NB - 1) ? &g_edge[b + 1][t * 8] // right nbr L-edge
                                            : &g_wmax[lane][DUMMY_OFF];
            ISSUE1(h, ph);
        }

        // ===== overlap phase (all waves): register-only neighbor exchange =====
        float Am = __shfl_up(A[3], 1, 64),  Qm = __shfl_up(Q[3], 1, 64),  Fm = __shfl_up(FQ[3], 1, 64);
        float Ap = __shfl_down(A[0], 1, 64), Qp = __shfl_down(Q[0], 1, 64), Fp = __shfl_down(FQ[0], 1, 64);

        float dFA[CPT], lapA[CPT], dFQ[CPT], lapQ[CPT];
        #pragma unroll
        for (int c = 0; c < CPT; ++c) {
            float Al = (c == 0) ? Am : A[c-1],  Ql = (c == 0) ? Qm : Q[c-1],  Fl = (c == 0) ? Fm : FQ[c-1];
            float Ar = (c == 3) ? Ap : A[c+1],  Qr = (c == 3) ? Qp : Q[c+1],  Fr = (c == 3) ? Fp : FQ[c+1];
            dFA[c]  = 0.5f * (Qr - Ql);
            lapA[c] = 0.5f * (Ar - 2.0f * A[c] + Al);
            dFQ[c]  = 0.5f * (Fr - Fl);
            lapQ[c] = 0.5f * (Qr - 2.0f * Q[c] + Ql);
        }
        // BC values depend only on step-t state: compute (incl. divide) pre-spin
        float qFix = 0.0f;
        if (isStart) qFix = s_inflow[t];
        if (isEnd)   qFix = (bet[3] * (sq[3] - 1.0f)) / Rtot;
        const float Pmid = bet[0] * (sq[0] - 1.0f);   // out value (midSlot threads)

        // ===== acquire smax/halos; no __syncthreads =====
        float lam, w;
        float hA = 0.0f, hQ = 0.0f, hF = 0.0f;
        if (wv == 0) {
            WAITVM();   // consume the early sample only now (latency hidden above)
            while (!__all((x0 != 0u) & (x1 != 0u) & (x2 != 0u) & (x3 != 0u) &
                          (x4 != 0u) & (x5 != 0u) & (h.x != 0u) & (h.z != 0u))) {
                POLL7(x0, x1, x2, x3, x4, x5, h, p0, p1, p2, p3, p4, p5, ph);
            }
            hA = __uint_as_float(h.x); hQ = __uint_as_float(h.y); hF = __uint_as_float(h.z);
            float m = fmaxf(fmaxf(fmaxf(__uint_as_float(x0), __uint_as_float(x1)),
                                  fmaxf(__uint_as_float(x2), __uint_as_float(x3))),
                            fmaxf(__uint_as_float(x4), __uint_as_float(x5)));
            m = wave_max64(m);
            const float smax = __int_as_float(__builtin_amdgcn_readlane(__float_as_int(m), 63));
            const float dt = ((float)(0.9 * 0.001)) / smax;   // ref op order
            lam = dt / 0.001f;
            w   = lam * smax;
            if (lane == 0) {
                unsigned long long v = ((unsigned long long)__float_as_uint(w) << 32)
                                       | (unsigned long long)__float_as_uint(lam);
                __hip_atomic_store(&s_lamw[t], v, __ATOMIC_RELEASE, __HIP_MEMORY_SCOPE_WORKGROUP);
            }
        } else {
            if (wv == WPB - 1) {
                WAITVM();
                while (!__all((h.x != 0u) & (h.z != 0u))) { POLL1(h, ph); }
                hA = __uint_as_float(h.x); hQ = __uint_as_float(h.y); hF = __uint_as_float(h.z);
            }
            unsigned long long lw;
            do {
                lw = __hip_atomic_load(&s_lamw[t], __ATOMIC_ACQUIRE, __HIP_MEMORY_SCOPE_WORKGROUP);
            } while ((unsigned int)lw == 0u);
            lam = __uint_as_float((unsigned int)lw);
            w   = __uint_as_float((unsigned int)(lw >> 32));
        }

        // ===== per-wave edge fixes (sE reads ordered by spin-detect transitivity) =====
        if (lane == 0 && (wv > 0 || b > 0)) {
            float Al, Ql, Fl;
            if (wv > 0) { Al = sE[par][wv-1][1][0]; Ql = sE[par][wv-1][1][1]; Fl = sE[par][wv-1][1][2]; }
            else        { Al = hA;                  Ql = hQ;                  Fl = hF; }
            dFA[0]  = 0.5f * (Q[1] - Ql);
            lapA[0] = 0.5f * (A[1] - 2.0f * A[0] + Al);
            dFQ[0]  = 0.5f * (FQ[1] - Fl);
            lapQ[0] = 0.5f * (Q[1] - 2.0f * Q[0] + Ql);
        }
        if (lane == 63 && (wv < WPB - 1 || b < NB - 1)) {
            float Ar, Qr, Fr;
            if (wv < WPB - 1) { Ar = sE[par][wv+1][0][0]; Qr = sE[par][wv+1][0][1]; Fr = sE[par][wv+1][0][2]; }
            else              { Ar = hA;                  Qr = hQ;                  Fr = hF; }
            dFA[3]  = 0.5f * (Qr - Q[2]);
            lapA[3] = 0.5f * (Ar - 2.0f * A[3] + A[2]);
            dFQ[3]  = 0.5f * (Fr - FQ[2]);
            lapQ[3] = 0.5f * (Qr - 2.0f * Q[3] + Q[2]);
        }

        // ===== update + BCs + clamp =====
        #pragma unroll
        for (int c = 0; c < CPT; ++c) {
            int i = base + c;
            if (act[c] && i > 0 && i < MM - 1) {
                A[c] = fmaf(w, lapA[c], fmaf(-lam, dFA[c], A[c]));
                Q[c] = fmaf(w, lapQ[c], fmaf(-lam, dFQ[c], Q[c]));
            }
        }
        if (isStart) Q[0] = qFix;
        if (isEnd)   Q[3] = qFix;
        #pragma unroll
        for (int c = 0; c < CPT; ++c) A[c] = fmaxf(A[c], 1e-6f);
        if (midSlot >= 0) out[t * 3 + midSlot] = Pmid;   // step-t output (off critical path)

        // ===== derived state for t+1 =====
        float uu[CPT];
        s4 = 0.0f;
        #pragma unroll
        for (int c = 0; c < CPT; ++c) {
            sq[c] = sqrtf(A[c] / A0v[c]);
            uu[c] = Q[c] / A[c];
            float cc = sqrtf(cbv[c] * sq[c]);
            s4 = fmaxf(s4, act[c] ? (fabsf(uu[c]) + cc) : 0.0f);
        }
        #pragma unroll
        for (int c = 0; c < CPT; ++c)
            FQ[c] = Q[c] * uu[c] + k2v[c] * A[c] * sq[c];

        // edge publish: one 16B unit, single instruction (no tearing window)
        const int n8 = (t + 1) * 8;
        if (pubL) { u32x4 ev = { __float_as_uint(A[0]), __float_as_uint(Q[0]), __float_as_uint(FQ[0]), 0u };
                    STORE_X4(&g_edge[b][n8], ev); }
        if (pubR) { u32x4 ev = { __float_as_uint(A[3]), __float_as_uint(Q[3]), __float_as_uint(FQ[3]), 0u };
                    STORE_X4(&g_edge[b][n8 + 4], ev); }

        // intra-block wave-edge state for t+1, then fence, then wmax publish LAST:
        // any observer of wmax[t+1] (spin or LDS-flag transitively) sees these writes.
        if (lane == 0)       { sE[npar][wv][0][0] = A[0]; sE[npar][wv][0][1] = Q[0]; sE[npar][wv][0][2] = FQ[0]; }
        else if (lane == 63) { sE[npar][wv][1][0] = A[3]; sE[npar][wv][1][1] = Q[3]; sE[npar][wv][1][2] = FQ[3]; }
        {
            float red = wave_max64(s4);
            FENCE_LDS();
            if (lane == 63) AG_STORE32(&g_wmax[gw][t + 1], __float_as_uint(red));
        }
    }
}

extern "C" void kernel_launch(void* const* d_in, const int* in_sizes, int n_in,
                              void* d_out, int out_size, void* d_ws, size_t ws_size,
                              hipStream_t stream) {
    (void)in_sizes; (void)n_in; (void)d_ws; (void)ws_size; (void)out_size;

    const float* Rs      = (const float*)d_in[0];
    const float* sim_dat = (const float*)d_in[1];
    const float* sdc     = (const float*)d_in[2];
    const float* inflow  = (const float*)d_in[3];
    float* out = (float*)d_out;

    hipLaunchKernelGGL(init_ws_kernel, dim3(240), dim3(256), 0, stream);

    // 88 blocks x 4 waves, ~2 KB LDS -> trivially co-resident on 256 CUs.
    hipLaunchKernelGGL(sim_kernel, dim3(NB), dim3(BS), 0, stream,
                       Rs, sim_dat, sdc, inflow, out);
}